// Round 1
// baseline (339.384 us; speedup 1.0000x reference)
//
#include <hip/hip_runtime.h>
#include <stdint.h>

// ReviewLoss: ce[i] = logsumexp(out[i,:]) - out[i, target[i]]
//   lam = k-th (0-indexed, descending) order statistic of ce, k = int(N*0.3)
//   result = mean over ALL N of (ce >= lam ? ce : 0)
//
// R10: fuse selection into the last-finishing ce block.
//  - Evidence: timed window includes ~158us of harness re-poison (copy 79.8 +
//    fill 78.7); our controllable budget is ~38us = ce(~25, near the 21us
//    131MB/6.3TB/s floor) + select(~9) + 2nd-launch gap(~4).
//  - The 16384-bin level-1 histogram is built DURING the ce phase with
//    fire-and-forget device-scope atomicAdd (1/row) into a global hist
//    (zeroed by a 65KB hipMemsetAsync). The last block to finish (atomic
//    done-counter, release/acquire __threadfence per G16) runs selection,
//    skipping the old pass-1 (full ce re-read + LDS hist build) and the
//    whole second kernel launch.
//  - ce blocks are 1024 threads (16 waves x 4 rows) so find_level_1024 runs
//    unchanged in the last block. LDS 69.8KB <= 80KB keeps 2 blocks/CU.

typedef unsigned int uint32;
typedef float vfloat4 __attribute__((ext_vector_type(4)));

#define LDNT(p) __builtin_nontemporal_load(p)

__device__ __forceinline__ float reduce_ce(vfloat4 v0, vfloat4 v1, vfloat4 v2,
                                           vfloat4 v3, float ot) {
  float m = fmaxf(fmaxf(fmaxf(v0.x, v0.y), fmaxf(v0.z, v0.w)),
                  fmaxf(fmaxf(fmaxf(v1.x, v1.y), fmaxf(v1.z, v1.w)),
                        fmaxf(fmaxf(fmaxf(v2.x, v2.y), fmaxf(v2.z, v2.w)),
                              fmaxf(fmaxf(v3.x, v3.y), fmaxf(v3.z, v3.w)))));
#pragma unroll
  for (int off = 1; off < 64; off <<= 1) m = fmaxf(m, __shfl_xor(m, off));
  float e = __expf(v0.x - m) + __expf(v0.y - m) + __expf(v0.z - m) + __expf(v0.w - m)
          + __expf(v1.x - m) + __expf(v1.y - m) + __expf(v1.z - m) + __expf(v1.w - m)
          + __expf(v2.x - m) + __expf(v2.y - m) + __expf(v2.z - m) + __expf(v2.w - m)
          + __expf(v3.x - m) + __expf(v3.y - m) + __expf(v3.z - m) + __expf(v3.w - m);
#pragma unroll
  for (int off = 1; off < 64; off <<= 1) e += __shfl_xor(e, off);
  return fmaxf((m - ot) + __logf(e), 0.0f);  // ce >= 0; kill -0.0
}

// Extract row[t] from the distributed register image. t is wave-uniform:
// quad q = t>>2 lives in set q>>6 of lane q&63, component t&3.
__device__ __forceinline__ float extract_elem(vfloat4 v0, vfloat4 v1,
                                              vfloat4 v2, vfloat4 v3, int t) {
  const int q = t >> 2;
  const int comp = t & 3;
  const int set = q >> 6;
  const int src = q & 63;
  vfloat4 v = (set == 0) ? v0 : (set == 1) ? v1 : (set == 2) ? v2 : v3;
  float val = (comp == 0) ? v.x : (comp == 1) ? v.y : (comp == 2) ? v.z : v.w;
  return __shfl(val, src);
}

// Find descending-rank `rank` in packed 16384-bin hist H (8192 words),
// 1024 threads, g[1024] scratch. Out: sel[0]=bin, sel[1]=rank-within-bin.
__device__ void find_level_1024(uint32* H, uint32* g, uint32 rank, int tid,
                                volatile uint32* sel) {
  uint32 c = 0;
#pragma unroll
  for (int j = 0; j < 8; ++j) {
    uint32 w = H[8 * tid + j];
    c += (w & 0xFFFFu) + (w >> 16);
  }
  g[tid] = c;
  __syncthreads();
  for (int off = 1; off < 1024; off <<= 1) {  // inclusive suffix scan
    uint32 v = g[tid] + ((tid + off < 1024) ? g[tid + off] : 0u);
    __syncthreads();
    g[tid] = v;
    __syncthreads();
  }
  uint32 SG = (tid + 1 < 1024) ? g[tid + 1] : 0u;
  if (SG <= rank && rank < g[tid]) { sel[0] = (uint32)tid; sel[1] = rank - SG; }
  __syncthreads();
  if (tid == 0) {
    uint32 grp = sel[0], kg = sel[1], acc = 0;
    for (int b = 15; b >= 0; --b) {
      uint32 bin = grp * 16u + (uint32)b;
      uint32 w = H[bin >> 1];
      uint32 cc = (bin & 1u) ? (w >> 16) : (w & 0xFFFFu);
      if (kg < acc + cc) { sel[0] = bin; sel[1] = kg - acc; break; }
      acc += cc;
    }
  }
  __syncthreads();
}

__global__ __launch_bounds__(1024) void fused_kernel(
    const float* __restrict__ logits, const int* __restrict__ target,
    float* __restrict__ ce, uint32* __restrict__ hist,
    uint32* __restrict__ done, float* __restrict__ out,
    int N, int C, int k) {
  __shared__ uint32 H[8192];     // packed 16384-bin hist (select phase only)
  __shared__ uint32 Cand[8192];  // candidate bit patterns
  __shared__ uint32 g[1024];
  __shared__ uint32 sel[2];
  __shared__ uint32 ccnt;
  __shared__ uint32 cnt8[8];
  __shared__ double wsum[16];
  __shared__ int s_last;

  const int tid = (int)threadIdx.x;
  const int lane = tid & 63;

  // ---------------- Phase 1: streaming ce + global level-1 hist ----------------
  {
    const int wave = (int)((blockIdx.x * blockDim.x + threadIdx.x) >> 6);
    const int r0 = wave * 4;
    if (r0 < N) {
      const int nv4 = C >> 2;  // C % 4 == 0 (C=1000 -> 250 quads)
      const vfloat4 NEG = {-INFINITY, -INFINITY, -INFINITY, -INFINITY};
      const vfloat4* p0 = (const vfloat4*)(logits + (size_t)r0 * (size_t)C);

      const bool has1 = (r0 + 1 < N);
      const bool has2 = (r0 + 2 < N);
      const bool has3 = (r0 + 3 < N);

      const int t0 = target[r0];
      const int t1 = has1 ? target[r0 + 1] : 0;
      const int t2 = has2 ? target[r0 + 2] : 0;
      const int t3 = has3 ? target[r0 + 3] : 0;

#define LOADQ(d0, d1, d2, d3, bp)                          \
  d0 = (lane       < nv4) ? LDNT((bp) + lane      ) : NEG; \
  d1 = (lane +  64 < nv4) ? LDNT((bp) + lane +  64) : NEG; \
  d2 = (lane + 128 < nv4) ? LDNT((bp) + lane + 128) : NEG; \
  d3 = (lane + 192 < nv4) ? LDNT((bp) + lane + 192) : NEG;

#define EMIT(row, cev)                                                    \
  if (lane == 0) {                                                        \
    ce[row] = (cev);                                                      \
    atomicAdd(&hist[__float_as_uint(cev) >> 17], 1u);                     \
  }

      vfloat4 a0, a1, a2, a3, b0, b1, b2, b3;
      const vfloat4* p1 = p0 + nv4;
      const vfloat4* p2 = p1 + nv4;
      const vfloat4* p3 = p2 + nv4;

      // prime: row r0
      LOADQ(a0, a1, a2, a3, p0);

      // row r0: prefetch r0+1, reduce a
      if (has1) { LOADQ(b0, b1, b2, b3, p1); }
      {
        float ot = extract_elem(a0, a1, a2, a3, t0);
        float cev = reduce_ce(a0, a1, a2, a3, ot);
        EMIT(r0, cev);
      }
      if (has1) {
        // row r0+1: prefetch r0+2 into a, reduce b
        if (has2) { LOADQ(a0, a1, a2, a3, p2); }
        {
          float ot = extract_elem(b0, b1, b2, b3, t1);
          float cev = reduce_ce(b0, b1, b2, b3, ot);
          EMIT(r0 + 1, cev);
        }
        if (has2) {
          // row r0+2: prefetch r0+3 into b, reduce a
          if (has3) { LOADQ(b0, b1, b2, b3, p3); }
          {
            float ot = extract_elem(a0, a1, a2, a3, t2);
            float cev = reduce_ce(a0, a1, a2, a3, ot);
            EMIT(r0 + 2, cev);
          }
          if (has3) {
            float ot = extract_elem(b0, b1, b2, b3, t3);
            float cev = reduce_ce(b0, b1, b2, b3, ot);
            EMIT(r0 + 3, cev);
          }
        }
      }
#undef LOADQ
#undef EMIT
    }
  }

  // ---------------- Handoff: last finishing block runs selection ----------------
  __syncthreads();
  if (tid == 0) {
    __threadfence();  // release: ce stores + hist atomics visible device-wide
    s_last = (atomicAdd(done, 1u) == (uint32)(gridDim.x - 1)) ? 1 : 0;
  }
  __syncthreads();
  if (!s_last) return;
  __threadfence();  // acquire: invalidate stale L1/L2 before reading ce/hist

  // ---------------- Phase 2: selection + filtered mean (one block) -------------
  const float4* ce4 = (const float4*)ce;
  const int N4 = N >> 2;  // N % 4 == 0

  // Load global level-1 hist into packed LDS H: bin b -> H[b>>1], halfword b&1.
#pragma unroll
  for (int j = 0; j < 8; ++j) {
    uint32 lo = hist[16 * tid + 2 * j];
    uint32 hi = hist[16 * tid + 2 * j + 1];
    H[8 * tid + j] = (lo & 0xFFFFu) | (hi << 16);
  }
  if (tid == 0) ccnt = 0;
  if (tid < 8) cnt8[tid] = 0;
  __syncthreads();

  find_level_1024(H, g, (uint32)k, tid, sel);
  const uint32 K = sel[0];
  const uint32 kr1 = sel[1];
  __syncthreads();

  // ---- Pass 2: sum key > K; ballot-collect key == K candidates ----
  double acc = 0.0;
  const int iters = (N4 + 1023) / 1024;
  for (int it = 0; it < iters; ++it) {   // uniform trip count for ballots
    int i = it * 1024 + tid;
    bool valid = (i < N4);
    float4 x = make_float4(0.f, 0.f, 0.f, 0.f);
    if (valid) x = ce4[i];
    float f[4] = {x.x, x.y, x.z, x.w};
#pragma unroll
    for (int j = 0; j < 4; ++j) {
      uint32 u = __float_as_uint(f[j]);
      uint32 key = u >> 17;
      if (valid && key > K) acc += (double)f[j];
      bool mine = valid && (key == K);
      unsigned long long mk = __ballot(mine);
      if (mk) {
        int src = (int)__ffsll(mk) - 1;
        uint32 base = 0;
        if (lane == src) base = atomicAdd(&ccnt, (uint32)__popcll(mk));
        base = (uint32)__shfl((int)base, src);
        if (mine) {
          uint32 p = base + (uint32)__popcll(mk & ((1ull << lane) - 1ull));
          if (p < 8192u) Cand[p] = u;
        }
      }
    }
  }
  __syncthreads();
  const uint32 c = (ccnt < 8192u) ? ccnt : 8192u;

  // ---- Level 2: hist over candidate bits 16..3 (14 bits) ----
  for (int j = tid; j < 8192; j += 1024) H[j] = 0;
  __syncthreads();
  for (uint32 j = (uint32)tid; j < c; j += 1024u) {
    uint32 k2 = (Cand[j] >> 3) & 0x3FFFu;
    atomicAdd(&H[k2 >> 1], (k2 & 1u) ? 0x10000u : 1u);
  }
  __syncthreads();
  find_level_1024(H, g, kr1, tid, sel);
  const uint32 B2 = sel[0];
  const uint32 kr2 = sel[1];
  __syncthreads();

  const uint32 lam_hi = (K << 17) | (B2 << 3);

  // ---- Level 3: 8 bins over bits 2..0 ----
  for (uint32 j = (uint32)tid; j < c; j += 1024u) {
    uint32 u = Cand[j];
    if ((u >> 3) == (lam_hi >> 3)) atomicAdd(&cnt8[u & 7u], 1u);
  }
  __syncthreads();
  if (tid == 0) {
    uint32 kg = kr2, a2 = 0;
    for (int b = 7; b >= 0; --b) {
      uint32 cc = cnt8[b];
      if (kg < a2 + cc) { sel[0] = lam_hi | (uint32)b; break; }
      a2 += cc;
    }
  }
  __syncthreads();
  const uint32 lam = sel[0];

  // ---- Add candidates >= lam (ties kept: matches where(ce<lam,0,ce)) ----
  for (uint32 j = (uint32)tid; j < c; j += 1024u) {
    uint32 u = Cand[j];
    if (u >= lam) acc += (double)__uint_as_float(u);
  }

  // ---- Reduce and write mean over all N ----
#pragma unroll
  for (int off = 1; off < 64; off <<= 1) acc += __shfl_xor(acc, off);
  if ((tid & 63) == 0) wsum[tid >> 6] = acc;
  __syncthreads();
  if (tid == 0) {
    double tsum = 0.0;
    for (int i = 0; i < 16; ++i) tsum += wsum[i];
    out[0] = (float)(tsum / (double)N);
  }
}

extern "C" void kernel_launch(void* const* d_in, const int* in_sizes, int n_in,
                              void* d_out, int out_size, void* d_ws, size_t ws_size,
                              hipStream_t stream) {
  const float* logits = (const float*)d_in[0];
  const int* target = (const int*)d_in[1];
  float* out = (float*)d_out;

  const int N = in_sizes[1];            // 32768
  const int C = in_sizes[0] / N;        // 1000
  const int k = (int)((double)N * 0.3); // 9830

  // Workspace layout: ce[N] | hist[16384] | done[1]
  float* ce = (float*)d_ws;
  uint32* hist = (uint32*)((char*)d_ws + (size_t)N * sizeof(float));
  uint32* done = hist + 16384;

  // Zero hist + done counter (workspace is re-poisoned every iteration).
  hipMemsetAsync(hist, 0, 16384 * sizeof(uint32) + sizeof(uint32), stream);

  // One fused kernel: 1024 threads = 16 waves x 4 rows = 64 rows/block.
  int nblk = (N + 63) / 64;  // 512
  fused_kernel<<<nblk, 1024, 0, stream>>>(logits, target, ce, hist, done, out,
                                          N, C, k);
}

// Round 2
// 211.452 us; speedup vs baseline: 1.6050x; 1.6050x over previous
//
#include <hip/hip_runtime.h>
#include <stdint.h>

// ReviewLoss: ce[i] = logsumexp(out[i,:]) - out[i, target[i]]
//   lam = k-th (0-indexed, descending) order statistic of ce, k = int(N*0.3)
//   result = mean over ALL N of (ce >= lam ? ce : 0)
//
// R11: de-contend the in-flight histogram.
//  - R10 post-mortem: fused_kernel was 185us (VALUBusy 5.5%, hbm 366 GB/s --
//    latency-serialized, not BW/compute). Cause: ce values concentrate at
//    ~logsumexp - x_t, so ~all 32768 hist atomicAdds hit 2-3 cache lines.
//    Device-scope atomics serialize at the coherence point (per-XCD L2s are
//    non-coherent), and each wave drains vmcnt(0) at the end barrier ->
//    whole grid queues behind ~13k same-line atomics (~160us).
//  - Fix: (a) 14-bit rotate swizzle swz(key)=((key&127)<<7)|(key>>7) (an
//    involution) spreads adjacent hot bins 512B apart -> one line per hot
//    bin; (b) 4x replication (rep = waveId&3, rep-major stride 16384) cuts
//    the hottest single address to ~200 adds over the 25us streaming window.
//  - Last block merges the 4 replicas (256KB coalesced) into packed LDS H
//    using the same involution, then selection proceeds as before.

typedef unsigned int uint32;
typedef float vfloat4 __attribute__((ext_vector_type(4)));

#define LDNT(p) __builtin_nontemporal_load(p)
#define NREP 4u

__device__ __forceinline__ float reduce_ce(vfloat4 v0, vfloat4 v1, vfloat4 v2,
                                           vfloat4 v3, float ot) {
  float m = fmaxf(fmaxf(fmaxf(v0.x, v0.y), fmaxf(v0.z, v0.w)),
                  fmaxf(fmaxf(fmaxf(v1.x, v1.y), fmaxf(v1.z, v1.w)),
                        fmaxf(fmaxf(fmaxf(v2.x, v2.y), fmaxf(v2.z, v2.w)),
                              fmaxf(fmaxf(v3.x, v3.y), fmaxf(v3.z, v3.w)))));
#pragma unroll
  for (int off = 1; off < 64; off <<= 1) m = fmaxf(m, __shfl_xor(m, off));
  float e = __expf(v0.x - m) + __expf(v0.y - m) + __expf(v0.z - m) + __expf(v0.w - m)
          + __expf(v1.x - m) + __expf(v1.y - m) + __expf(v1.z - m) + __expf(v1.w - m)
          + __expf(v2.x - m) + __expf(v2.y - m) + __expf(v2.z - m) + __expf(v2.w - m)
          + __expf(v3.x - m) + __expf(v3.y - m) + __expf(v3.z - m) + __expf(v3.w - m);
#pragma unroll
  for (int off = 1; off < 64; off <<= 1) e += __shfl_xor(e, off);
  return fmaxf((m - ot) + __logf(e), 0.0f);  // ce >= 0; kill -0.0
}

// Extract row[t] from the distributed register image. t is wave-uniform:
// quad q = t>>2 lives in set q>>6 of lane q&63, component t&3.
__device__ __forceinline__ float extract_elem(vfloat4 v0, vfloat4 v1,
                                              vfloat4 v2, vfloat4 v3, int t) {
  const int q = t >> 2;
  const int comp = t & 3;
  const int set = q >> 6;
  const int src = q & 63;
  vfloat4 v = (set == 0) ? v0 : (set == 1) ? v1 : (set == 2) ? v2 : v3;
  float val = (comp == 0) ? v.x : (comp == 1) ? v.y : (comp == 2) ? v.z : v.w;
  return __shfl(val, src);
}

// Find descending-rank `rank` in packed 16384-bin hist H (8192 words),
// 1024 threads, g[1024] scratch. Out: sel[0]=bin, sel[1]=rank-within-bin.
__device__ void find_level_1024(uint32* H, uint32* g, uint32 rank, int tid,
                                volatile uint32* sel) {
  uint32 c = 0;
#pragma unroll
  for (int j = 0; j < 8; ++j) {
    uint32 w = H[8 * tid + j];
    c += (w & 0xFFFFu) + (w >> 16);
  }
  g[tid] = c;
  __syncthreads();
  for (int off = 1; off < 1024; off <<= 1) {  // inclusive suffix scan
    uint32 v = g[tid] + ((tid + off < 1024) ? g[tid + off] : 0u);
    __syncthreads();
    g[tid] = v;
    __syncthreads();
  }
  uint32 SG = (tid + 1 < 1024) ? g[tid + 1] : 0u;
  if (SG <= rank && rank < g[tid]) { sel[0] = (uint32)tid; sel[1] = rank - SG; }
  __syncthreads();
  if (tid == 0) {
    uint32 grp = sel[0], kg = sel[1], acc = 0;
    for (int b = 15; b >= 0; --b) {
      uint32 bin = grp * 16u + (uint32)b;
      uint32 w = H[bin >> 1];
      uint32 cc = (bin & 1u) ? (w >> 16) : (w & 0xFFFFu);
      if (kg < acc + cc) { sel[0] = bin; sel[1] = kg - acc; break; }
      acc += cc;
    }
  }
  __syncthreads();
}

__global__ __launch_bounds__(1024) void fused_kernel(
    const float* __restrict__ logits, const int* __restrict__ target,
    float* __restrict__ ce, uint32* __restrict__ hist,
    uint32* __restrict__ done, float* __restrict__ out,
    int N, int C, int k) {
  __shared__ uint32 H[8192];     // packed 16384-bin hist (select phase only)
  __shared__ uint32 Cand[8192];  // candidate bit patterns
  __shared__ uint32 g[1024];
  __shared__ uint32 sel[2];
  __shared__ uint32 ccnt;
  __shared__ uint32 cnt8[8];
  __shared__ double wsum[16];
  __shared__ int s_last;

  const int tid = (int)threadIdx.x;
  const int lane = tid & 63;

  // ---------------- Phase 1: streaming ce + replicated global hist -------------
  {
    const int wave = (int)((blockIdx.x * blockDim.x + threadIdx.x) >> 6);
    const int r0 = wave * 4;
    if (r0 < N) {
      const int nv4 = C >> 2;  // C % 4 == 0 (C=1000 -> 250 quads)
      const vfloat4 NEG = {-INFINITY, -INFINITY, -INFINITY, -INFINITY};
      const vfloat4* p0 = (const vfloat4*)(logits + (size_t)r0 * (size_t)C);

      const bool has1 = (r0 + 1 < N);
      const bool has2 = (r0 + 2 < N);
      const bool has3 = (r0 + 3 < N);

      const int t0 = target[r0];
      const int t1 = has1 ? target[r0 + 1] : 0;
      const int t2 = has2 ? target[r0 + 2] : 0;
      const int t3 = has3 ? target[r0 + 3] : 0;

      const uint32 repbase = ((uint32)wave & (NREP - 1u)) * 16384u;

#define LOADQ(d0, d1, d2, d3, bp)                          \
  d0 = (lane       < nv4) ? LDNT((bp) + lane      ) : NEG; \
  d1 = (lane +  64 < nv4) ? LDNT((bp) + lane +  64) : NEG; \
  d2 = (lane + 128 < nv4) ? LDNT((bp) + lane + 128) : NEG; \
  d3 = (lane + 192 < nv4) ? LDNT((bp) + lane + 192) : NEG;

      // swz is an involution on 14 bits: rotate by 7. Adjacent bins -> 512B apart.
#define EMIT(row, cev)                                                    \
  if (lane == 0) {                                                        \
    ce[row] = (cev);                                                      \
    uint32 key_ = __float_as_uint(cev) >> 17;                             \
    uint32 a_ = ((key_ & 127u) << 7) | (key_ >> 7);                       \
    atomicAdd(&hist[repbase + a_], 1u);                                   \
  }

      vfloat4 a0, a1, a2, a3, b0, b1, b2, b3;
      const vfloat4* p1 = p0 + nv4;
      const vfloat4* p2 = p1 + nv4;
      const vfloat4* p3 = p2 + nv4;

      // prime: row r0
      LOADQ(a0, a1, a2, a3, p0);

      // row r0: prefetch r0+1, reduce a
      if (has1) { LOADQ(b0, b1, b2, b3, p1); }
      {
        float ot = extract_elem(a0, a1, a2, a3, t0);
        float cev = reduce_ce(a0, a1, a2, a3, ot);
        EMIT(r0, cev);
      }
      if (has1) {
        // row r0+1: prefetch r0+2 into a, reduce b
        if (has2) { LOADQ(a0, a1, a2, a3, p2); }
        {
          float ot = extract_elem(b0, b1, b2, b3, t1);
          float cev = reduce_ce(b0, b1, b2, b3, ot);
          EMIT(r0 + 1, cev);
        }
        if (has2) {
          // row r0+2: prefetch r0+3 into b, reduce a
          if (has3) { LOADQ(b0, b1, b2, b3, p3); }
          {
            float ot = extract_elem(a0, a1, a2, a3, t2);
            float cev = reduce_ce(a0, a1, a2, a3, ot);
            EMIT(r0 + 2, cev);
          }
          if (has3) {
            float ot = extract_elem(b0, b1, b2, b3, t3);
            float cev = reduce_ce(b0, b1, b2, b3, ot);
            EMIT(r0 + 3, cev);
          }
        }
      }
#undef LOADQ
#undef EMIT
    }
  }

  // ---------------- Handoff: last finishing block runs selection ----------------
  __syncthreads();
  if (tid == 0) {
    __threadfence();  // release: ce stores + hist atomics visible device-wide
    s_last = (atomicAdd(done, 1u) == (uint32)(gridDim.x - 1)) ? 1 : 0;
  }
  __syncthreads();
  if (!s_last) return;
  __threadfence();  // acquire: invalidate stale caches before reading ce/hist

  // ---------------- Phase 2: selection + filtered mean (one block) -------------
  const float4* ce4 = (const float4*)ce;
  const int N4 = N >> 2;  // N % 4 == 0

  // Merge NREP replicas of the swizzled global hist into packed LDS H.
  // Thread tid owns swizzled addrs [16tid, 16tid+16): coalesced 64B per rep.
  for (int j = tid; j < 8192; j += 1024) H[j] = 0;
  if (tid == 0) ccnt = 0;
  if (tid < 8) cnt8[tid] = 0;
  __syncthreads();
  {
    uint32 cnt[16];
#pragma unroll
    for (int j = 0; j < 16; ++j) cnt[j] = 0;
#pragma unroll
    for (uint32 r = 0; r < NREP; ++r) {
      const uint4* p = (const uint4*)(hist + r * 16384u + 16u * (uint32)tid);
#pragma unroll
      for (int q = 0; q < 4; ++q) {
        uint4 v = p[q];
        cnt[4 * q + 0] += v.x;
        cnt[4 * q + 1] += v.y;
        cnt[4 * q + 2] += v.z;
        cnt[4 * q + 3] += v.w;
      }
    }
#pragma unroll
    for (int j = 0; j < 16; ++j) {
      if (cnt[j]) {
        uint32 a = 16u * (uint32)tid + (uint32)j;    // swizzled addr
        uint32 bin = ((a & 127u) << 7) | (a >> 7);   // logical bin (involution)
        atomicAdd(&H[bin >> 1], (bin & 1u) ? (cnt[j] << 16) : cnt[j]);
      }
    }
  }
  __syncthreads();

  find_level_1024(H, g, (uint32)k, tid, sel);
  const uint32 K = sel[0];
  const uint32 kr1 = sel[1];
  __syncthreads();

  // ---- Pass 2: sum key > K; ballot-collect key == K candidates ----
  double acc = 0.0;
  const int iters = (N4 + 1023) / 1024;
  for (int it = 0; it < iters; ++it) {   // uniform trip count for ballots
    int i = it * 1024 + tid;
    bool valid = (i < N4);
    float4 x = make_float4(0.f, 0.f, 0.f, 0.f);
    if (valid) x = ce4[i];
    float f[4] = {x.x, x.y, x.z, x.w};
#pragma unroll
    for (int j = 0; j < 4; ++j) {
      uint32 u = __float_as_uint(f[j]);
      uint32 key = u >> 17;
      if (valid && key > K) acc += (double)f[j];
      bool mine = valid && (key == K);
      unsigned long long mk = __ballot(mine);
      if (mk) {
        int src = (int)__ffsll(mk) - 1;
        uint32 base = 0;
        if (lane == src) base = atomicAdd(&ccnt, (uint32)__popcll(mk));
        base = (uint32)__shfl((int)base, src);
        if (mine) {
          uint32 p = base + (uint32)__popcll(mk & ((1ull << lane) - 1ull));
          if (p < 8192u) Cand[p] = u;
        }
      }
    }
  }
  __syncthreads();
  const uint32 c = (ccnt < 8192u) ? ccnt : 8192u;

  // ---- Level 2: hist over candidate bits 16..3 (14 bits) ----
  for (int j = tid; j < 8192; j += 1024) H[j] = 0;
  __syncthreads();
  for (uint32 j = (uint32)tid; j < c; j += 1024u) {
    uint32 k2 = (Cand[j] >> 3) & 0x3FFFu;
    atomicAdd(&H[k2 >> 1], (k2 & 1u) ? 0x10000u : 1u);
  }
  __syncthreads();
  find_level_1024(H, g, kr1, tid, sel);
  const uint32 B2 = sel[0];
  const uint32 kr2 = sel[1];
  __syncthreads();

  const uint32 lam_hi = (K << 17) | (B2 << 3);

  // ---- Level 3: 8 bins over bits 2..0 ----
  for (uint32 j = (uint32)tid; j < c; j += 1024u) {
    uint32 u = Cand[j];
    if ((u >> 3) == (lam_hi >> 3)) atomicAdd(&cnt8[u & 7u], 1u);
  }
  __syncthreads();
  if (tid == 0) {
    uint32 kg = kr2, a2 = 0;
    for (int b = 7; b >= 0; --b) {
      uint32 cc = cnt8[b];
      if (kg < a2 + cc) { sel[0] = lam_hi | (uint32)b; break; }
      a2 += cc;
    }
  }
  __syncthreads();
  const uint32 lam = sel[0];

  // ---- Add candidates >= lam (ties kept: matches where(ce<lam,0,ce)) ----
  for (uint32 j = (uint32)tid; j < c; j += 1024u) {
    uint32 u = Cand[j];
    if (u >= lam) acc += (double)__uint_as_float(u);
  }

  // ---- Reduce and write mean over all N ----
#pragma unroll
  for (int off = 1; off < 64; off <<= 1) acc += __shfl_xor(acc, off);
  if ((tid & 63) == 0) wsum[tid >> 6] = acc;
  __syncthreads();
  if (tid == 0) {
    double tsum = 0.0;
    for (int i = 0; i < 16; ++i) tsum += wsum[i];
    out[0] = (float)(tsum / (double)N);
  }
}

extern "C" void kernel_launch(void* const* d_in, const int* in_sizes, int n_in,
                              void* d_out, int out_size, void* d_ws, size_t ws_size,
                              hipStream_t stream) {
  const float* logits = (const float*)d_in[0];
  const int* target = (const int*)d_in[1];
  float* out = (float*)d_out;

  const int N = in_sizes[1];            // 32768
  const int C = in_sizes[0] / N;        // 1000
  const int k = (int)((double)N * 0.3); // 9830

  // Workspace layout: ce[N] | hist[NREP*16384] | done[1]
  float* ce = (float*)d_ws;
  uint32* hist = (uint32*)((char*)d_ws + (size_t)N * sizeof(float));
  uint32* done = hist + NREP * 16384u;

  // Zero hist replicas + done counter (workspace is re-poisoned every iter).
  hipMemsetAsync(hist, 0, (NREP * 16384u + 1u) * sizeof(uint32), stream);

  // One fused kernel: 1024 threads = 16 waves x 4 rows = 64 rows/block.
  int nblk = (N + 63) / 64;  // 512
  fused_kernel<<<nblk, 1024, 0, stream>>>(logits, target, ce, hist, done, out,
                                          N, C, k);
}

// Round 3
// 191.164 us; speedup vs baseline: 1.7754x; 1.1061x over previous
//
#include <hip/hip_runtime.h>
#include <stdint.h>

// ReviewLoss: ce[i] = logsumexp(out[i,:]) - out[i, target[i]]
//   lam = k-th (0-indexed, descending) order statistic of ce, k = int(N*0.3)
//   result = mean over ALL N of (ce >= lam ? ce : 0)
//
// R12: revert to the proven two-kernel R9 structure (196.2us); both fusion
// attempts (R10/R11) lost ~13us to 1024-thread block coupling + extra
// memset launch. This round attacks select_kernel's serialization: the old
// find_level_1024 suffix scan was 10 rounds x 2 __syncthreads + LDS
// round-trips (~3us/call, called twice). Replaced with a hierarchical
// shfl scan: 6 guarded __shfl_down rounds in-wave (no barriers), 16 wave
// totals in LDS, owning thread drills its own 16 bins. 2 barriers/call.
// ce_kernel is byte-identical to R9.

typedef unsigned int uint32;
typedef float vfloat4 __attribute__((ext_vector_type(4)));

#define LDNT(p) __builtin_nontemporal_load(p)

__device__ __forceinline__ float reduce_ce(vfloat4 v0, vfloat4 v1, vfloat4 v2,
                                           vfloat4 v3, float ot) {
  float m = fmaxf(fmaxf(fmaxf(v0.x, v0.y), fmaxf(v0.z, v0.w)),
                  fmaxf(fmaxf(fmaxf(v1.x, v1.y), fmaxf(v1.z, v1.w)),
                        fmaxf(fmaxf(fmaxf(v2.x, v2.y), fmaxf(v2.z, v2.w)),
                              fmaxf(fmaxf(v3.x, v3.y), fmaxf(v3.z, v3.w)))));
#pragma unroll
  for (int off = 1; off < 64; off <<= 1) m = fmaxf(m, __shfl_xor(m, off));
  float e = __expf(v0.x - m) + __expf(v0.y - m) + __expf(v0.z - m) + __expf(v0.w - m)
          + __expf(v1.x - m) + __expf(v1.y - m) + __expf(v1.z - m) + __expf(v1.w - m)
          + __expf(v2.x - m) + __expf(v2.y - m) + __expf(v2.z - m) + __expf(v2.w - m)
          + __expf(v3.x - m) + __expf(v3.y - m) + __expf(v3.z - m) + __expf(v3.w - m);
#pragma unroll
  for (int off = 1; off < 64; off <<= 1) e += __shfl_xor(e, off);
  return fmaxf((m - ot) + __logf(e), 0.0f);  // ce >= 0; kill -0.0
}

// Extract row[t] from the distributed register image. t is wave-uniform:
// quad q = t>>2 lives in set q>>6 of lane q&63, component t&3.
__device__ __forceinline__ float extract_elem(vfloat4 v0, vfloat4 v1,
                                              vfloat4 v2, vfloat4 v3, int t) {
  const int q = t >> 2;
  const int comp = t & 3;
  const int set = q >> 6;
  const int src = q & 63;
  vfloat4 v = (set == 0) ? v0 : (set == 1) ? v1 : (set == 2) ? v2 : v3;
  float val = (comp == 0) ? v.x : (comp == 1) ? v.y : (comp == 2) ? v.z : v.w;
  return __shfl(val, src);
}

// 4 rows per wave, one-row-ahead pipeline. No LDS, no barriers, no
// dependent global loads (ot comes from registers). (Unchanged from R9.)
__global__ __launch_bounds__(256) void ce_kernel(
    const float* __restrict__ logits, const int* __restrict__ target,
    float* __restrict__ ce, int N, int C) {
  const int lane = (int)(threadIdx.x & 63);
  const int wave = (int)((blockIdx.x * blockDim.x + threadIdx.x) >> 6);
  const int r0 = wave * 4;
  if (r0 >= N) return;

  const int nv4 = C >> 2;  // C % 4 == 0 (C=1000 -> 250 quads)
  const vfloat4 NEG = {-INFINITY, -INFINITY, -INFINITY, -INFINITY};
  const vfloat4* p0 = (const vfloat4*)(logits + (size_t)r0 * (size_t)C);

  const bool has1 = (r0 + 1 < N);
  const bool has2 = (r0 + 2 < N);
  const bool has3 = (r0 + 3 < N);

  // Hoisted target loads (independent, issued with the first LOADQ).
  const int t0 = target[r0];
  const int t1 = has1 ? target[r0 + 1] : 0;
  const int t2 = has2 ? target[r0 + 2] : 0;
  const int t3 = has3 ? target[r0 + 3] : 0;

#define LOADQ(d0, d1, d2, d3, bp)                          \
  d0 = (lane       < nv4) ? LDNT((bp) + lane      ) : NEG; \
  d1 = (lane +  64 < nv4) ? LDNT((bp) + lane +  64) : NEG; \
  d2 = (lane + 128 < nv4) ? LDNT((bp) + lane + 128) : NEG; \
  d3 = (lane + 192 < nv4) ? LDNT((bp) + lane + 192) : NEG;

  vfloat4 a0, a1, a2, a3, b0, b1, b2, b3;
  const vfloat4* p1 = p0 + nv4;
  const vfloat4* p2 = p1 + nv4;
  const vfloat4* p3 = p2 + nv4;

  // prime: row r0
  LOADQ(a0, a1, a2, a3, p0);

  // row r0: prefetch r0+1, reduce a
  if (has1) { LOADQ(b0, b1, b2, b3, p1); }
  {
    float ot = extract_elem(a0, a1, a2, a3, t0);
    float cev = reduce_ce(a0, a1, a2, a3, ot);
    if (lane == 0) ce[r0] = cev;
  }
  if (!has1) return;

  // row r0+1: prefetch r0+2 into a, reduce b
  if (has2) { LOADQ(a0, a1, a2, a3, p2); }
  {
    float ot = extract_elem(b0, b1, b2, b3, t1);
    float cev = reduce_ce(b0, b1, b2, b3, ot);
    if (lane == 0) ce[r0 + 1] = cev;
  }
  if (!has2) return;

  // row r0+2: prefetch r0+3 into b, reduce a
  if (has3) { LOADQ(b0, b1, b2, b3, p3); }
  {
    float ot = extract_elem(a0, a1, a2, a3, t2);
    float cev = reduce_ce(a0, a1, a2, a3, ot);
    if (lane == 0) ce[r0 + 2] = cev;
  }
  if (!has3) return;

  // row r0+3: reduce b
  {
    float ot = extract_elem(b0, b1, b2, b3, t3);
    float cev = reduce_ce(b0, b1, b2, b3, ot);
    if (lane == 0) ce[r0 + 3] = cev;
  }
#undef LOADQ
}

// ---------------- selection + filtered mean (single block) ----------------

// Find descending-rank `rank` in packed 16384-bin hist H (8192 words),
// 1024 threads. Hierarchical shfl suffix scan: 6 in-wave __shfl_down
// rounds (no barriers) + 16 wave totals in LDS + owning-thread bin drill.
// 2 __syncthreads total (vs ~23 in the old LDS-scan version).
// Out: sel[0]=bin, sel[1]=rank-within-bin.
__device__ void find_level_1024(uint32* H, uint32 rank, int tid,
                                volatile uint32* sel) {
  __shared__ uint32 wl[16];
  const int lane = tid & 63;
  const int w = tid >> 6;

  // per-thread count over its 16 bins (8 packed words)
  uint32 c = 0;
#pragma unroll
  for (int j = 0; j < 8; ++j) {
    uint32 word = H[8 * tid + j];
    c += (word & 0xFFFFu) + (word >> 16);
  }

  // in-wave inclusive suffix sum s(lane) = sum_{l>=lane} c_l
  uint32 s = c;
#pragma unroll
  for (int off = 1; off < 64; off <<= 1) {
    uint32 t = __shfl_down(s, off);
    if (lane + off < 64) s += t;
  }
  if (lane == 0) wl[w] = s;  // wave total
  __syncthreads();

  // suffix of later waves (broadcast LDS reads, wave-uniform loop)
  uint32 E = 0;
  for (int v = w + 1; v < 16; ++v) E += wl[v];

  // inclusive global suffix at tid; owner satisfies g-c <= rank < g
  uint32 g = s + E;
  if (rank < g && rank >= g - c) {
    uint32 kg = rank - (g - c);
    uint32 acc = 0;
#pragma unroll
    for (int b = 15; b >= 0; --b) {
      uint32 word = H[8 * tid + (b >> 1)];
      uint32 cc = (b & 1) ? (word >> 16) : (word & 0xFFFFu);
      if (kg < acc + cc) {
        sel[0] = 16u * (uint32)tid + (uint32)b;
        sel[1] = kg - acc;
        break;
      }
      acc += cc;
    }
  }
  __syncthreads();
}

__global__ __launch_bounds__(1024) void select_kernel(
    const float* __restrict__ ce, float* __restrict__ out, int N, int k) {
  __shared__ uint32 H[8192];     // packed 16384-bin hist (reused level 2)
  __shared__ uint32 Cand[8192];  // candidate bit patterns
  __shared__ uint32 sel[2];
  __shared__ uint32 ccnt;
  __shared__ uint32 cnt8[8];
  __shared__ double wsum[16];
  const int tid = (int)threadIdx.x;
  const int lane = tid & 63;
  const float4* ce4 = (const float4*)ce;
  const int N4 = N >> 2;  // N % 4 == 0

  if (tid == 0) ccnt = 0;
  if (tid < 8) cnt8[tid] = 0;
  for (int j = tid; j < 8192; j += 1024) H[j] = 0;
  __syncthreads();

  // ---- Pass 1: 16384-bin hist of key = u >> 17 (ce >= 0 -> key <= 16320) ----
  for (int i = tid; i < N4; i += 1024) {
    float4 x = ce4[i];
    uint32 k0 = __float_as_uint(x.x) >> 17;
    uint32 k1 = __float_as_uint(x.y) >> 17;
    uint32 k2 = __float_as_uint(x.z) >> 17;
    uint32 k3 = __float_as_uint(x.w) >> 17;
    atomicAdd(&H[k0 >> 1], (k0 & 1u) ? 0x10000u : 1u);
    atomicAdd(&H[k1 >> 1], (k1 & 1u) ? 0x10000u : 1u);
    atomicAdd(&H[k2 >> 1], (k2 & 1u) ? 0x10000u : 1u);
    atomicAdd(&H[k3 >> 1], (k3 & 1u) ? 0x10000u : 1u);
  }
  __syncthreads();
  find_level_1024(H, (uint32)k, tid, sel);
  const uint32 K = sel[0];
  const uint32 kr1 = sel[1];
  __syncthreads();

  // ---- Pass 2: sum key > K; ballot-collect key == K candidates ----
  double acc = 0.0;
  const int iters = (N4 + 1023) / 1024;
  for (int it = 0; it < iters; ++it) {   // uniform trip count for ballots
    int i = it * 1024 + tid;
    bool valid = (i < N4);
    float4 x = make_float4(0.f, 0.f, 0.f, 0.f);
    if (valid) x = ce4[i];
    float f[4] = {x.x, x.y, x.z, x.w};
#pragma unroll
    for (int j = 0; j < 4; ++j) {
      uint32 u = __float_as_uint(f[j]);
      uint32 key = u >> 17;
      if (valid && key > K) acc += (double)f[j];
      bool mine = valid && (key == K);
      unsigned long long mk = __ballot(mine);
      if (mk) {
        int src = (int)__ffsll(mk) - 1;
        uint32 base = 0;
        if (lane == src) base = atomicAdd(&ccnt, (uint32)__popcll(mk));
        base = (uint32)__shfl((int)base, src);
        if (mine) {
          uint32 p = base + (uint32)__popcll(mk & ((1ull << lane) - 1ull));
          if (p < 8192u) Cand[p] = u;
        }
      }
    }
  }
  __syncthreads();
  const uint32 c = (ccnt < 8192u) ? ccnt : 8192u;

  // ---- Level 2: hist over candidate bits 16..3 (14 bits) ----
  for (int j = tid; j < 8192; j += 1024) H[j] = 0;
  __syncthreads();
  for (uint32 j = (uint32)tid; j < c; j += 1024u) {
    uint32 k2 = (Cand[j] >> 3) & 0x3FFFu;
    atomicAdd(&H[k2 >> 1], (k2 & 1u) ? 0x10000u : 1u);
  }
  __syncthreads();
  find_level_1024(H, kr1, tid, sel);
  const uint32 B2 = sel[0];
  const uint32 kr2 = sel[1];
  __syncthreads();

  const uint32 lam_hi = (K << 17) | (B2 << 3);

  // ---- Level 3: 8 bins over bits 2..0 ----
  for (uint32 j = (uint32)tid; j < c; j += 1024u) {
    uint32 u = Cand[j];
    if ((u >> 3) == (lam_hi >> 3)) atomicAdd(&cnt8[u & 7u], 1u);
  }
  __syncthreads();
  if (tid == 0) {
    uint32 kg = kr2, a2 = 0;
    for (int b = 7; b >= 0; --b) {
      uint32 cc = cnt8[b];
      if (kg < a2 + cc) { sel[0] = lam_hi | (uint32)b; break; }
      a2 += cc;
    }
  }
  __syncthreads();
  const uint32 lam = sel[0];

  // ---- Add candidates >= lam (ties kept: matches where(ce<lam,0,ce)) ----
  for (uint32 j = (uint32)tid; j < c; j += 1024u) {
    uint32 u = Cand[j];
    if (u >= lam) acc += (double)__uint_as_float(u);
  }

  // ---- Reduce and write mean over all N ----
#pragma unroll
  for (int off = 1; off < 64; off <<= 1) acc += __shfl_xor(acc, off);
  if ((tid & 63) == 0) wsum[tid >> 6] = acc;
  __syncthreads();
  if (tid == 0) {
    double tsum = 0.0;
    for (int i = 0; i < 16; ++i) tsum += wsum[i];
    out[0] = (float)(tsum / (double)N);
  }
}

extern "C" void kernel_launch(void* const* d_in, const int* in_sizes, int n_in,
                              void* d_out, int out_size, void* d_ws, size_t ws_size,
                              hipStream_t stream) {
  const float* logits = (const float*)d_in[0];
  const int* target = (const int*)d_in[1];
  float* out = (float*)d_out;

  const int N = in_sizes[1];            // 32768
  const int C = in_sizes[0] / N;        // 1000
  const int k = (int)((double)N * 0.3); // 9830

  float* ce = (float*)d_ws;

  // K1: 4 rows per wave, 16 rows per 256-thread block.
  int nblk = (N + 15) / 16;  // 2048
  ce_kernel<<<nblk, 256, 0, stream>>>(logits, target, ce, N, C);

  // K2: single block: hist + select + filtered mean. No memset needed.
  select_kernel<<<1, 1024, 0, stream>>>(ce, out, N, k);
}